// Round 6
// baseline (190.404 us; speedup 1.0000x reference)
//
#include <hip/hip_runtime.h>
#include <hip/hip_fp16.h>

#define EPS 1e-5f

constexpr int B = 8;
constexpr int V = 100000;
constexpr int F = 200000;
constexpr int U = 1024;
constexpr int T = 110000;
constexpr int CAP = 24;                     // max faces/vertex (data max ~20)

constexpr int NBUK = (V + 127) / 128;       // 782 buckets, 128 vertices each
constexpr int N4   = (3 * F) / 4;           // 150000 int4 edge-quads
constexpr int EB   = (N4 + 255) / 256;      // 586 edge blocks

// R5 lesson: FN role is traffic-bound, not latency-bound (FQ=8/ILP and
// FQ=2/TLP both pin at ~2.5 TB/s, 45-50us). Random vi gathers force every
// XCD's private L2 to cache the whole 12.8 MB vertsT -> ~50 MB duplicated
// fabric fetch. Fix: batch-per-XCD split (batch = blockIdx%8) so each XCD
// gathers only its 1.2 MB verts slice (L2-resident), reading verts directly.
constexpr int FCH  = (F + 255) / 256;       // 782 face chunks
constexpr int FNB2 = FCH * 8;               // 6256 FN blocks (chunk x batch)
constexpr int TQ   = 2;                     // samples per thread (corner role)
constexpr int CPB  = (T / TQ + 255) / 256;  // 215 blocks
constexpr int VQ   = 2;                     // vertices per thread (k7)

// packed half4 (8 B): x,y,z in halves, w pad
struct alignas(8) h4 { __half2 a, b; };
__device__ inline h4 pack_h4(float x, float y, float z) {
    h4 r; r.a = __floats2half2_rn(x, y); r.b = __floats2half2_rn(z, 0.0f);
    return r;
}
__device__ inline float3 unpack_h4(h4 v) {
    float2 xy = __half22float2(v.a);
    float2 zw = __half22float2(v.b);
    return make_float3(xy.x, xy.y, zw.x);
}

// 16 B corner record: 3x21-bit indices packed in (lo,hi) + half weights
struct alignas(16) Corner16 { unsigned lo, hi; __half2 w01; __half2 w2_; };
__device__ inline Corner16 pack_corner(int i0, int i1, int i2,
                                       float w0, float w1, float w2) {
    unsigned long long x = (unsigned long long)(unsigned)i0
                         | ((unsigned long long)(unsigned)i1 << 21)
                         | ((unsigned long long)(unsigned)i2 << 42);
    Corner16 c;
    c.lo = (unsigned)x;
    c.hi = (unsigned)(x >> 32);
    c.w01 = __floats2half2_rn(w0, w1);
    c.w2_ = __floats2half2_rn(w2, 0.0f);
    return c;
}

// ---------------------------------------------------------------------------
// K1: per-block bucket histograms only (the vertsT transpose is gone — the
// FN role now reads verts directly, batch-localized per XCD).
// R3 lesson stands: no global-atomic ELL (cross-XCD 4 B scatter amplifies).
// ---------------------------------------------------------------------------
__global__ void k1_pre(const int* __restrict__ vi,
                       int* __restrict__ hist) {    // (EB, NBUK)
    __shared__ int lh[NBUK];
    int k = blockIdx.x;
    for (int i = threadIdx.x; i < NBUK; i += 256) lh[i] = 0;
    __syncthreads();
    int m4 = k * 256 + threadIdx.x;
    if (m4 < N4) {
        int4 e = ((const int4*)vi)[m4];
        atomicAdd(&lh[e.x >> 7], 1);
        atomicAdd(&lh[e.y >> 7], 1);
        atomicAdd(&lh[e.z >> 7], 1);
        atomicAdd(&lh[e.w >> 7], 1);
    }
    __syncthreads();
    for (int b = threadIdx.x; b < NBUK; b += 256) hist[k * NBUK + b] = lh[b];
}

// ---------------------------------------------------------------------------
// K2: three roles, no device atomics:
//   [0, FNB2):           face normals, batch-per-XCD: batch = blk%8 (XCD
//                        round-robin), face = (blk>>3)*256+tid. Each XCD's
//                        gather target = its 1.2 MB verts slice, L2-resident.
//                        Writes fnT (8,F) batch-major, fully coalesced.
//   [FNB2, +CPB):        corner precompute, TQ=2 samples per thread
//   [FNB2+CPB, +NBUK):   per-bucket exclusive scan over EB block counts
// ---------------------------------------------------------------------------
__global__ void k2_fused(const int* __restrict__ vi,          // (F,3) flat
                         const float* __restrict__ verts,     // (B,V,3)
                         h4* __restrict__ fnT,                // (8,F)
                         const int* __restrict__ index_image, // (U,U,3)
                         const float* __restrict__ bary_image,// (U,U,3)
                         const float* __restrict__ vt,        // (T,2)
                         Corner16* __restrict__ corners,      // (T,4)
                         int* __restrict__ hist,              // (EB,NBUK) -> off
                         int* __restrict__ tot) {             // (NBUK)
    int blk = blockIdx.x;

    if (blk < FNB2) {
        int b = blk & 7;                     // == XCD under round-robin
        int f = (blk >> 3) * 256 + threadIdx.x;
        if (f >= F) return;

        const float* vb = verts + (size_t)b * V * 3;
        int i0 = vi[f * 3 + 0];
        int i1 = vi[f * 3 + 1];
        int i2 = vi[f * 3 + 2];
        const float* q0 = vb + (size_t)i0 * 3;
        const float* q1 = vb + (size_t)i1 * 3;
        const float* q2 = vb + (size_t)i2 * 3;
        float p0x = q0[0], p0y = q0[1], p0z = q0[2];
        float p1x = q1[0], p1y = q1[1], p1z = q1[2];
        float p2x = q2[0], p2y = q2[1], p2z = q2[2];

        float e1x = p1x - p0x, e1y = p1y - p0y, e1z = p1z - p0z;
        float e2x = p2x - p0x, e2y = p2y - p0y, e2z = p2z - p0z;

        float nx = e1y * e2z - e1z * e2y;
        float ny = e1z * e2x - e1x * e2z;
        float nz = e1x * e2y - e1y * e2x;

        float norm = sqrtf(nx * nx + ny * ny + nz * nz);
        float inv = (norm < EPS) ? 1.0f : (1.0f / norm);
        fnT[(size_t)b * F + f] = pack_h4(nx * inv, ny * inv, nz * inv);
        return;
    }

    if (blk < FNB2 + CPB) {
        int tbase = (blk - FNB2) * 256 + threadIdx.x;
        if (tbase >= T / TQ) return;
#pragma unroll
        for (int qq = 0; qq < TQ; ++qq) {
            int t = tbase + qq * (T / TQ);

            float gx = vt[t * 2 + 0];
            float gy = vt[t * 2 + 1];
            float ix = gx * (float)U - 0.5f;
            float iy = gy * (float)U - 0.5f;

            float x0f = floorf(ix);
            float y0f = floorf(iy);
            int x0 = (int)x0f;
            int y0 = (int)y0f;
            float wx1 = ix - x0f, wx0 = 1.0f - wx1;
            float wy1 = iy - y0f, wy0 = 1.0f - wy1;

#pragma unroll
            for (int c = 0; c < 4; ++c) {
                int cy = c >> 1, cx = c & 1;
                int y = y0 + cy;
                int x = x0 + cx;
                int i0 = 0, i1 = 0, i2 = 0;
                float w0 = 0.0f, w1 = 0.0f, w2 = 0.0f;
                if (x >= 0 && x < U && y >= 0 && y < U) {
                    float w = (cy ? wy1 : wy0) * (cx ? wx1 : wx0);
                    int pix = y * U + x;
                    int j0 = index_image[pix * 3 + 0];
                    int j1 = index_image[pix * 3 + 1];
                    int j2 = index_image[pix * 3 + 2];
                    float m = (j0 != -1 && j1 != -1 && j2 != -1) ? 1.0f : 0.0f;
                    float wm = w * m;
                    i0 = min(max(j0, 0), V - 1);
                    i1 = min(max(j1, 0), V - 1);
                    i2 = min(max(j2, 0), V - 1);
                    w0 = wm * bary_image[pix * 3 + 0];
                    w1 = wm * bary_image[pix * 3 + 1];
                    w2 = wm * bary_image[pix * 3 + 2];
                }
                corners[t * 4 + c] = pack_corner(i0, i1, i2, w0, w1, w2);
            }
        }
        return;
    }

    // --- per-bucket scan: bucket b, exclusive-prefix hist[k][b] over k ---
    {
        __shared__ int part[256];
        int b = blk - FNB2 - CPB;
        int th = threadIdx.x;
        int k0 = th * 3;  // 256*3 = 768 >= EB(586)
        int c0 = (k0     < EB) ? hist[(k0    ) * NBUK + b] : 0;
        int c1 = (k0 + 1 < EB) ? hist[(k0 + 1) * NBUK + b] : 0;
        int c2 = (k0 + 2 < EB) ? hist[(k0 + 2) * NBUK + b] : 0;
        int local = c0 + c1 + c2;
        part[th] = local;
        __syncthreads();
        for (int off = 1; off < 256; off <<= 1) {
            int x = (th >= off) ? part[th - off] : 0;
            __syncthreads();
            part[th] += x;
            __syncthreads();
        }
        int excl = part[th] - local;
        if (th == 255) tot[b] = part[255];
        if (k0     < EB) hist[(k0    ) * NBUK + b] = excl;
        if (k0 + 1 < EB) hist[(k0 + 1) * NBUK + b] = excl + c0;
        if (k0 + 2 < EB) hist[(k0 + 2) * NBUK + b] = excl + c0 + c1;
    }
}

// Redundant per-block exclusive scan of tot -> pre[0..NBUK] in LDS.
// MUST be called by ALL NT threads of the block (contains barriers).
template <int NT>
__device__ inline void scan_base(const int* __restrict__ tot,
                                 int* pre, int* part) {
    constexpr int CH = (NBUK + NT - 1) / NT;
    int th = threadIdx.x;
    int loc[CH];
    int local = 0;
#pragma unroll
    for (int j = 0; j < CH; ++j) {
        int idx = th * CH + j;
        int c = (idx < NBUK) ? tot[idx] : 0;
        loc[j] = local;           // exclusive within chunk
        local += c;
    }
    part[th] = local;
    __syncthreads();
    for (int off = 1; off < NT; off <<= 1) {
        int x = (th >= off) ? part[th - off] : 0;
        __syncthreads();
        part[th] += x;
        __syncthreads();
    }
    int excl = part[th] - local;
#pragma unroll
    for (int j = 0; j < CH; ++j) {
        int idx = th * CH + j;
        if (idx < NBUK) pre[idx] = excl + loc[j];
    }
    if (th == NT - 1) pre[NBUK] = part[NT - 1];
    __syncthreads();
}

// ---------------------------------------------------------------------------
// K4: two roles:
//   [0, EB):        scatter edges to bucket regions (LDS rank atomics only)
//   [EB, EB+FCH):   fnT (8,F) -> fn (F,8) transpose. Thread f: 8 coalesced
//                   8 B loads (one per batch slice) + one contiguous 64 B
//                   store — restores the (F,8) row layout k5/k6 rely on for
//                   8-lane line sharing, without cross-XCD false sharing.
// ---------------------------------------------------------------------------
__global__ void k4_scatter(const int* __restrict__ vi,
                           const int* __restrict__ off,   // (EB,NBUK)
                           const int* __restrict__ tot,   // (NBUK)
                           int* __restrict__ pairs,       // (3F)
                           const h4* __restrict__ fnT,    // (8,F)
                           h4* __restrict__ fn) {         // (F,8)
    int blk = blockIdx.x;
    if (blk >= EB) {
        int f = (blk - EB) * 256 + threadIdx.x;
        if (f >= F) return;
        h4 row[8];
#pragma unroll
        for (int b = 0; b < 8; ++b) row[b] = fnT[(size_t)b * F + f];
        float4* dst = (float4*)(fn + (size_t)f * 8);
        const float4* src = (const float4*)row;
#pragma unroll
        for (int i = 0; i < 4; ++i) dst[i] = src[i];
        return;
    }

    __shared__ int lh[NBUK];
    __shared__ int pre[NBUK + 1];
    __shared__ int part[256];
    scan_base<256>(tot, pre, part);

    int k = blk;
    for (int i = threadIdx.x; i < NBUK; i += 256) lh[i] = 0;
    __syncthreads();
    int m4 = k * 256 + threadIdx.x;
    if (m4 >= N4) return;
    int4 e = ((const int4*)vi)[m4];
    int be = m4 * 4;
    int vv[4] = {e.x, e.y, e.z, e.w};
#pragma unroll
    for (int j = 0; j < 4; ++j) {
        int v = vv[j];
        int b = v >> 7;
        int r = atomicAdd(&lh[b], 1);
        int pos = pre[b] + off[k * NBUK + b] + r;
        pairs[pos] = ((v & 127) << 18) | ((be + j) / 3);
    }
}

// ---------------------------------------------------------------------------
// K5: per-bucket ELL build in LDS + fp16 fn gather + normalize -> fp16 vn.
// 512 threads/block (8 waves; NBUK=782 blocks is structurally ~3/CU).
// Gather loop unrolled x2 so two 64 B fn gathers are always in flight.
// ---------------------------------------------------------------------------
__global__ __launch_bounds__(512) void k5_gather(
        const int* __restrict__ pairs,
        const int* __restrict__ tot,
        const h4* __restrict__ fn,       // (F,8)
        h4* __restrict__ vn) {           // (V,8)
    __shared__ int cnt[128];
    __shared__ int rows[128 * CAP];      // 12.3 KB
    __shared__ int pre[NBUK + 1];
    __shared__ int part[512];
    scan_base<512>(tot, pre, part);      // all 512 threads, uniform barriers

    int tid = threadIdx.x;
    if (tid < 128) cnt[tid] = 0;
    __syncthreads();

    int b = blockIdx.x;
    int start = pre[b], end = pre[b + 1];
    for (int i = start + tid; i < end; i += 512) {
        int pk = pairs[i];
        int vl = pk >> 18;
        int f = pk & 0x3FFFF;
        int pos = atomicAdd(&cnt[vl], 1);
        if (pos < CAP) rows[vl * CAP + pos] = f;
    }
    __syncthreads();

    int v0 = b << 7;
    for (int id = tid; id < 128 * 8; id += 512) {
        int vl = id >> 3, b8 = id & 7;
        int v = v0 + vl;
        if (v >= V) continue;
        int deg = min(cnt[vl], CAP);
        float ax = 0.0f, ay = 0.0f, az = 0.0f;
        int j = 0;
        for (; j + 1 < deg; j += 2) {
            h4 r0 = fn[(size_t)rows[vl * CAP + j] * 8 + b8];
            h4 r1 = fn[(size_t)rows[vl * CAP + j + 1] * 8 + b8];
            float3 n0 = unpack_h4(r0);
            float3 n1 = unpack_h4(r1);
            ax += n0.x + n1.x; ay += n0.y + n1.y; az += n0.z + n1.z;
        }
        if (j < deg) {
            float3 n = unpack_h4(fn[(size_t)rows[vl * CAP + j] * 8 + b8]);
            ax += n.x; ay += n.y; az += n.z;
        }
        float nn = sqrtf(ax * ax + ay * ay + az * az);
        float inv = (nn < EPS) ? 1.0f : (1.0f / nn);
        vn[(size_t)v * 8 + b8] = pack_h4(ax * inv, ay * inv, az * inv);
    }
}

// ---------------------------------------------------------------------------
// K6: sample with 16 B packed corners, 1 sample per thread -> 3438 blocks.
// 8 lanes share each t -> corner loads broadcast, vn gathers share lines.
// ---------------------------------------------------------------------------
__global__ void sample_points(const h4* __restrict__ vn,           // (V,8)
                              const Corner16* __restrict__ corners,// (T,4)
                              h4* __restrict__ vals) {             // (T,8)
    int id = blockIdx.x * blockDim.x + threadIdx.x;
    if (id >= T * 8) return;
    int b = id & 7;
    int t = id >> 3;

    float ax = 0.0f, ay = 0.0f, az = 0.0f;
    Corner16 cr[4];
#pragma unroll
    for (int c = 0; c < 4; ++c) cr[c] = corners[t * 4 + c];
    h4 q[12];
#pragma unroll
    for (int c = 0; c < 4; ++c) {
        unsigned long long x = (unsigned long long)cr[c].lo
                             | ((unsigned long long)cr[c].hi << 32);
        int i0 = (int)(x & 0x1FFFFF);
        int i1 = (int)((x >> 21) & 0x1FFFFF);
        int i2 = (int)(x >> 42);
        q[c * 3 + 0] = vn[(size_t)i0 * 8 + b];
        q[c * 3 + 1] = vn[(size_t)i1 * 8 + b];
        q[c * 3 + 2] = vn[(size_t)i2 * 8 + b];
    }
#pragma unroll
    for (int c = 0; c < 4; ++c) {
        float2 w01 = __half22float2(cr[c].w01);
        float w2 = __low2float(cr[c].w2_);
        float3 q0 = unpack_h4(q[c * 3 + 0]);
        float3 q1 = unpack_h4(q[c * 3 + 1]);
        float3 q2 = unpack_h4(q[c * 3 + 2]);
        ax += w01.x * q0.x + w01.y * q1.x + w2 * q2.x;
        ay += w01.x * q0.y + w01.y * q1.y + w2 * q2.y;
        az += w01.x * q0.z + w01.y * q1.z + w2 * q2.z;
    }
    vals[(size_t)t * 8 + b] = pack_h4(ax, ay, az);
}

// ---------------------------------------------------------------------------
// K7: out[b,v,:] = mean over K=2 of vals[v2uv[v,k], b]. VQ=2 vertices per
// thread (4 gathers in flight). fp32 output.
// ---------------------------------------------------------------------------
__global__ void gather_out(const h4* __restrict__ vals,     // (T,8)
                           const int* __restrict__ v2uv,    // (V,2)
                           float* __restrict__ out) {       // (B,V,3)
    int id = blockIdx.x * blockDim.x + threadIdx.x;
    if (id >= (V / VQ) * 8) return;
    int b = id & 7;
    int vb = id >> 3;

    int t0[VQ], t1[VQ];
    h4 xa[VQ], ya[VQ];
#pragma unroll
    for (int s = 0; s < VQ; ++s) {
        int v = vb + s * (V / VQ);
        t0[s] = v2uv[v * 2 + 0];
        t1[s] = v2uv[v * 2 + 1];
    }
#pragma unroll
    for (int s = 0; s < VQ; ++s) {
        xa[s] = vals[(size_t)t0[s] * 8 + b];
        ya[s] = vals[(size_t)t1[s] * 8 + b];
    }
#pragma unroll
    for (int s = 0; s < VQ; ++s) {
        int v = vb + s * (V / VQ);
        float3 x = unpack_h4(xa[s]);
        float3 y = unpack_h4(ya[s]);
        float* o = out + (size_t)b * V * 3 + (size_t)v * 3;
        o[0] = 0.5f * (x.x + y.x);
        o[1] = 0.5f * (x.y + y.y);
        o[2] = 0.5f * (x.z + y.z);
    }
}

extern "C" void kernel_launch(void* const* d_in, const int* in_sizes, int n_in,
                              void* d_out, int out_size, void* d_ws, size_t ws_size,
                              hipStream_t stream) {
    const float* verts   = (const float*)d_in[0]; // (B,V,3)
    const float* bary    = (const float*)d_in[1]; // (U,U,3)
    const float* vt      = (const float*)d_in[2]; // (T,2)
    const int*   vi      = (const int*)d_in[3];   // (F,3)
    const int*   idx_img = (const int*)d_in[4];   // (U,U,3)
    const int*   v2uv    = (const int*)d_in[5];   // (V,2)
    float* out = (float*)d_out;

    // Workspace (~37 MB), aliased by stream-ordered disjoint lifetimes:
    //   region A (12.8 MB): fnT (8,F) h4 (K2 w, K4 r) -> vn h4 6.4 MB (K5 w, K6 r)
    //   region B (12.8 MB): fn (F,8) h4 (K4 w, K5 r) -> vals h4 7.04 MB (K6 w, K7 r)
    //   region C (7.04 MB): corners 16 B packed (K2 w, K6 r)
    //   region D: hist 1.83 MB, tot 3 KB, pairs 2.4 MB
    h4*       fnT     = (h4*)d_ws;                  // 8*F
    h4*       vn      = (h4*)d_ws;                  // alias (V*8)
    h4*       fn      = (h4*)((char*)d_ws + (size_t)F * 8 * sizeof(h4));
    h4*       vals    = fn;                         // alias
    Corner16* corners = (Corner16*)((char*)fn + (size_t)F * 8 * sizeof(h4));
    int*      hist    = (int*)(corners + (size_t)T * 4);  // (EB,NBUK)
    int*      tot     = hist + (size_t)EB * NBUK;   // NBUK
    int*      pairs   = tot + NBUK;                 // 3F

    const int BLK = 256;
    k1_pre<<<EB, BLK, 0, stream>>>(vi, hist);
    k2_fused<<<FNB2 + CPB + NBUK, BLK, 0, stream>>>(
        vi, verts, fnT, idx_img, bary, vt, corners, hist, tot);
    k4_scatter<<<EB + FCH, BLK, 0, stream>>>(vi, hist, tot, pairs, fnT, fn);
    k5_gather<<<NBUK, 512, 0, stream>>>(pairs, tot, fn, vn);
    sample_points<<<(T * 8 + BLK - 1) / BLK, BLK, 0, stream>>>(
        vn, corners, vals);
    gather_out<<<((V / VQ) * 8 + BLK - 1) / BLK, BLK, 0, stream>>>(
        vals, v2uv, out);
}